// Round 1
// baseline (74.028 us; speedup 1.0000x reference)
//
#include <hip/hip_runtime.h>
#include <hip/hip_bf16.h>

// WaveletConv: Haar DWT -> 4x (64x64 channel mix) -> inverse Haar, fused.
// B=8, C=64, H=256, W=256. Subband grid 128x128.
// Block = 256 threads (4 waves) handles (b, i, 64 j-sites): 64KB in, 64KB out.

using bf16x8 = __attribute__((ext_vector_type(8))) short;  // 8 bf16 (4 VGPRs)
using f32x4  = __attribute__((ext_vector_type(4))) float;  // MFMA acc

__device__ inline unsigned short f2bf(float v) {
    __hip_bfloat16 h = __float2bfloat16(v);
    return __builtin_bit_cast(unsigned short, h);
}

// ---------------------------------------------------------------------------
// Prep kernel: bake per-lane MFMA A-fragments for the 4 weight matrices and
// the 4 sign-combined bias vectors into d_ws.
//   afrag element index: ((band*2 + ks)*4 + mt)*512 + lane*8 + i
//     holds bf16( W_band[o=16*mt+(lane&15)][c=32*ks+(lane>>4)*8+i] )
//   bcomb[d*64+o] = 0.5*(bLL + sH(di)*bLH + sW(dj)*bHL + sH*sW*bHH), d=di*2+dj
// ---------------------------------------------------------------------------
__global__ __launch_bounds__(256) void wvc_prep(
    const float* __restrict__ wLL, const float* __restrict__ bLL,
    const float* __restrict__ wLH, const float* __restrict__ bLH,
    const float* __restrict__ wHL, const float* __restrict__ bHL,
    const float* __restrict__ wHH, const float* __restrict__ bHH,
    unsigned short* __restrict__ afrag, float* __restrict__ bcomb)
{
    int t = threadIdx.x;
    const float* Ws[4] = {wLL, wLH, wHL, wHH};
    for (int idx = t; idx < 16384; idx += 256) {
        int i    = idx & 7;
        int lane = (idx >> 3) & 63;
        int mt   = (idx >> 9) & 3;
        int ks   = (idx >> 11) & 1;
        int band = (idx >> 12) & 3;
        int o = mt * 16 + (lane & 15);
        int c = ks * 32 + (lane >> 4) * 8 + i;
        afrag[idx] = f2bf(Ws[band][o * 64 + c]);
    }
    if (t < 64) {
        float b0 = bLL[t], b1 = bLH[t], b2 = bHL[t], b3 = bHH[t];
        bcomb[0 * 64 + t] = 0.5f * (b0 + b1 + b2 + b3);
        bcomb[1 * 64 + t] = 0.5f * (b0 + b1 - b2 - b3);
        bcomb[2 * 64 + t] = 0.5f * (b0 - b1 + b2 - b3);
        bcomb[3 * 64 + t] = 0.5f * (b0 - b1 - b2 + b3);
    }
}

// ---------------------------------------------------------------------------
// Main kernel.
// grid = (2 j-tiles, 128 i-rows, 8 batches), block = 256.
// LDS: Sb[site][band][c] bf16 (XOR-swizzled, 32KB) + A-fragments (32KB).
// ---------------------------------------------------------------------------
__global__ __launch_bounds__(256, 2) void wvc_main(
    const float* __restrict__ x,
    const unsigned short* __restrict__ afrag_g,
    const float* __restrict__ bcomb,
    float* __restrict__ out)
{
    __shared__ __align__(16) unsigned char lds_sb[32768];  // 64 sites * 512B
    __shared__ __align__(16) unsigned char lds_af[32768];  // A-fragments

    const int tid  = threadIdx.x;
    const int b    = blockIdx.z;
    const int irow = blockIdx.y;
    const int jt   = blockIdx.x;
    const int w0   = jt * 128;     // input w base (64 sites * 2)
    const int h0   = irow * 2;     // input h base

    // ---- load A-fragments global -> LDS (32KB, once per block) ----
    #pragma unroll
    for (int it = 0; it < 8; ++it) {
        int idx = it * 256 + tid;  // 2048 x 16B
        ((float4*)lds_af)[idx] = ((const float4*)afrag_g)[idx];
    }

    // ---- stage subbands: x -> Haar -> bf16 -> swizzled LDS ----
    const int j   = tid & 63;      // site within tile
    const int cq0 = tid >> 6;      // 0..3
    const float* xb = x + (size_t)b * 64 * 65536 + (size_t)h0 * 256 + w0 + 2 * j;

    for (int p = 0; p < 4; ++p) {
        int cq = p * 4 + cq0;      // channel quad 0..15
        unsigned short sLL[4], sLH[4], sHL[4], sHH[4];
        #pragma unroll
        for (int k = 0; k < 4; ++k) {
            int c = cq * 4 + k;
            const float* px = xb + (size_t)c * 65536;
            float2 r0 = *(const float2*)px;          // row h0,   w=2j,2j+1
            float2 r1 = *(const float2*)(px + 256);  // row h0+1
            float a  = r0.x + r0.y, bm = r0.x - r0.y;
            float cp = r1.x + r1.y, dm = r1.x - r1.y;
            sLL[k] = f2bf(0.5f * (a + cp));
            sLH[k] = f2bf(0.5f * (a - cp));
            sHL[k] = f2bf(0.5f * (bm + dm));
            sHH[k] = f2bf(0.5f * (bm - dm));
        }
        int sbase = j * 512;
        int swz   = (cq * 8) ^ ((j & 7) << 4);  // byte offset in 128B band row
        *(ushort4*)(&lds_sb[sbase + 0 * 128 + swz]) = make_ushort4(sLL[0], sLL[1], sLL[2], sLL[3]);
        *(ushort4*)(&lds_sb[sbase + 1 * 128 + swz]) = make_ushort4(sLH[0], sLH[1], sLH[2], sLH[3]);
        *(ushort4*)(&lds_sb[sbase + 2 * 128 + swz]) = make_ushort4(sHL[0], sHL[1], sHL[2], sHL[3]);
        *(ushort4*)(&lds_sb[sbase + 3 * 128 + swz]) = make_ushort4(sHH[0], sHH[1], sHH[2], sHH[3]);
    }

    __syncthreads();

    // ---- MFMA: per wave, 16 sites x 64 out-ch x 4 bands, K=64 ----
    const int l    = tid & 63;
    const int wv   = tid >> 6;
    const int site = wv * 16 + (l & 15);
    const int lg   = l >> 4;

    f32x4 acc[4][4];  // [band][mt]
    #pragma unroll
    for (int bd = 0; bd < 4; ++bd)
        #pragma unroll
        for (int mt = 0; mt < 4; ++mt)
            acc[bd][mt] = (f32x4){0.f, 0.f, 0.f, 0.f};

    #pragma unroll
    for (int bd = 0; bd < 4; ++bd) {
        #pragma unroll
        for (int ks = 0; ks < 2; ++ks) {
            int boff = site * 512 + bd * 128 + ((lg * 16 + ks * 64) ^ ((site & 7) << 4));
            bf16x8 bfr = *(const bf16x8*)(&lds_sb[boff]);
            #pragma unroll
            for (int mt = 0; mt < 4; ++mt) {
                int aoff = (((bd * 2 + ks) * 4 + mt) * 64 + l) * 16;
                bf16x8 afr = *(const bf16x8*)(&lds_af[aoff]);
                acc[bd][mt] = __builtin_amdgcn_mfma_f32_16x16x32_bf16(afr, bfr, acc[bd][mt], 0, 0, 0);
            }
        }
    }

    // ---- epilogue: inverse Haar recombine + bias, coalesced float2 stores ----
    const int wb = w0 + 2 * site;
    float* ob = out + (size_t)b * 64 * 65536 + (size_t)h0 * 256 + wb;
    #pragma unroll
    for (int mt = 0; mt < 4; ++mt) {
        #pragma unroll
        for (int r = 0; r < 4; ++r) {
            int o = mt * 16 + lg * 4 + r;
            float y0 = acc[0][mt][r];  // LL
            float y1 = acc[1][mt][r];  // LH (high-H)
            float y2 = acc[2][mt][r];  // HL (high-W)
            float y3 = acc[3][mt][r];  // HH
            float s01 = y0 + y1, d01 = y0 - y1;
            float s23 = y2 + y3, d23 = y2 - y3;
            float e00 = 0.5f * (s01 + s23) + bcomb[o];
            float e01 = 0.5f * (s01 - s23) + bcomb[64 + o];
            float e10 = 0.5f * (d01 + d23) + bcomb[128 + o];
            float e11 = 0.5f * (d01 - d23) + bcomb[192 + o];
            float* po = ob + (size_t)o * 65536;
            float2 v0; v0.x = e00; v0.y = e01;
            float2 v1; v1.x = e10; v1.y = e11;
            *(float2*)po         = v0;
            *(float2*)(po + 256) = v1;
        }
    }
}

extern "C" void kernel_launch(void* const* d_in, const int* in_sizes, int n_in,
                              void* d_out, int out_size, void* d_ws, size_t ws_size,
                              hipStream_t stream) {
    const float* x   = (const float*)d_in[0];
    const float* wLL = (const float*)d_in[1];
    const float* bLL = (const float*)d_in[2];
    const float* wLH = (const float*)d_in[3];
    const float* bLH = (const float*)d_in[4];
    const float* wHL = (const float*)d_in[5];
    const float* bHL = (const float*)d_in[6];
    const float* wHH = (const float*)d_in[7];
    const float* bHH = (const float*)d_in[8];
    float* out = (float*)d_out;

    unsigned short* afrag = (unsigned short*)d_ws;              // 32768 B
    float* bcomb = (float*)((char*)d_ws + 32768);               // 1024 B

    wvc_prep<<<1, 256, 0, stream>>>(wLL, bLL, wLH, bLH, wHL, bHL, wHH, bHH,
                                    afrag, bcomb);
    wvc_main<<<dim3(2, 128, 8), 256, 0, stream>>>(x, afrag, bcomb, out);
}

// Round 2
// 71.741 us; speedup vs baseline: 1.0319x; 1.0319x over previous
//
#include <hip/hip_runtime.h>
#include <hip/hip_bf16.h>

// WaveletConv: Haar DWT -> 4x (64x64 channel mix) -> inverse Haar, fused.
// B=8, C=64, H=256, W=256. Subband grid 128x128.
// Block = 256 threads (4 waves) handles (b, i, 64 j-sites): 64KB in, 64KB out.
// R1: LDS 64KB->32KB (A-frags stream from L2), float4 staging, b128 LDS writes,
//     launch_bounds(256,4) -> target 4 blocks/CU (16 waves/CU).

using bf16x8  = __attribute__((ext_vector_type(8))) short;          // 8 bf16
using f32x4   = __attribute__((ext_vector_type(4))) float;          // MFMA acc
using ushort8 = __attribute__((ext_vector_type(8))) unsigned short; // 16B LDS store

__device__ inline unsigned short f2bf(float v) {
    __hip_bfloat16 h = __float2bfloat16(v);
    return __builtin_bit_cast(unsigned short, h);
}

// ---------------------------------------------------------------------------
// Prep kernel: bake per-lane MFMA A-fragments for the 4 weight matrices and
// the 4 sign-combined bias vectors into d_ws.
//   afrag element index: ((band*2 + ks)*4 + mt)*512 + lane*8 + i
//     holds bf16( W_band[o=16*mt+(lane&15)][c=32*ks+(lane>>4)*8+i] )
//   bcomb[d*64+o] = 0.5*(bLL + sH(di)*bLH + sW(dj)*bHL + sH*sW*bHH), d=di*2+dj
// ---------------------------------------------------------------------------
__global__ __launch_bounds__(256) void wvc_prep(
    const float* __restrict__ wLL, const float* __restrict__ bLL,
    const float* __restrict__ wLH, const float* __restrict__ bLH,
    const float* __restrict__ wHL, const float* __restrict__ bHL,
    const float* __restrict__ wHH, const float* __restrict__ bHH,
    unsigned short* __restrict__ afrag, float* __restrict__ bcomb)
{
    int t = threadIdx.x;
    const float* Ws[4] = {wLL, wLH, wHL, wHH};
    for (int idx = t; idx < 16384; idx += 256) {
        int i    = idx & 7;
        int lane = (idx >> 3) & 63;
        int mt   = (idx >> 9) & 3;
        int ks   = (idx >> 11) & 1;
        int band = (idx >> 12) & 3;
        int o = mt * 16 + (lane & 15);
        int c = ks * 32 + (lane >> 4) * 8 + i;
        afrag[idx] = f2bf(Ws[band][o * 64 + c]);
    }
    if (t < 64) {
        float b0 = bLL[t], b1 = bLH[t], b2 = bHL[t], b3 = bHH[t];
        bcomb[0 * 64 + t] = 0.5f * (b0 + b1 + b2 + b3);
        bcomb[1 * 64 + t] = 0.5f * (b0 + b1 - b2 - b3);
        bcomb[2 * 64 + t] = 0.5f * (b0 - b1 + b2 - b3);
        bcomb[3 * 64 + t] = 0.5f * (b0 - b1 - b2 + b3);
    }
}

// ---------------------------------------------------------------------------
// Main kernel.
// grid = (2 j-tiles, 128 i-rows, 8 batches), block = 256 (4 waves).
// LDS: Sb[site][band][c] bf16, XOR-swizzled by (site>>1)&7, 32KB total.
// ---------------------------------------------------------------------------
__global__ __launch_bounds__(256, 4) void wvc_main(
    const float* __restrict__ x,
    const unsigned short* __restrict__ afrag_g,
    const float* __restrict__ bcomb,
    float* __restrict__ out)
{
    __shared__ __align__(16) unsigned char lds_sb[32768];  // 64 sites * 512B

    const int tid  = threadIdx.x;
    const int b    = blockIdx.z;
    const int irow = blockIdx.y;
    const int jt   = blockIdx.x;
    const int w0   = jt * 128;     // input w base (64 sites * 2)
    const int h0   = irow * 2;     // input h base

    // ---- stage subbands: x -> Haar -> bf16 -> swizzled LDS ----
    // thread owns site pair (2sp, 2sp+1) and channel group cg (8 channels)
    const int sp = tid & 31;
    const int cg = tid >> 5;
    const float* xb = x + (size_t)b * 64 * 65536 + (size_t)h0 * 256 + w0
                        + 4 * sp + (size_t)cg * 8 * 65536;

    ushort8 v[4][2];  // [band][site parity], 8 channels each
    #pragma unroll
    for (int c = 0; c < 8; ++c) {
        const float* px = xb + (size_t)c * 65536;
        f32x4 r0 = *(const f32x4*)px;          // row h0:   w = 4sp .. 4sp+3
        f32x4 r1 = *(const f32x4*)(px + 256);  // row h0+1
        // site 0 (w = 4sp, 4sp+1)
        float a0 = r0[0] + r0[1], m0 = r0[0] - r0[1];
        float c0 = r1[0] + r1[1], d0 = r1[0] - r1[1];
        v[0][0][c] = f2bf(0.5f * (a0 + c0));
        v[1][0][c] = f2bf(0.5f * (a0 - c0));
        v[2][0][c] = f2bf(0.5f * (m0 + d0));
        v[3][0][c] = f2bf(0.5f * (m0 - d0));
        // site 1 (w = 4sp+2, 4sp+3)
        float a1 = r0[2] + r0[3], m1 = r0[2] - r0[3];
        float c1 = r1[2] + r1[3], d1 = r1[2] - r1[3];
        v[0][1][c] = f2bf(0.5f * (a1 + c1));
        v[1][1][c] = f2bf(0.5f * (a1 - c1));
        v[2][1][c] = f2bf(0.5f * (m1 + d1));
        v[3][1][c] = f2bf(0.5f * (m1 - d1));
    }
    // both sites of the pair share swizzle key (s>>1)&7 == sp&7
    {
        const int off = (cg * 16) ^ ((sp & 7) << 4);
        #pragma unroll
        for (int p = 0; p < 2; ++p) {
            const int base = (2 * sp + p) * 512;
            #pragma unroll
            for (int bd = 0; bd < 4; ++bd)
                *(ushort8*)(&lds_sb[base + bd * 128 + off]) = v[bd][p];
        }
    }

    __syncthreads();

    // ---- MFMA: per wave, 16 sites x 64 out-ch x 4 bands, K=64 ----
    // A-fragments stream directly from global (L2-resident, 32KB shared).
    const int l    = tid & 63;
    const int wv   = tid >> 6;
    const int site = wv * 16 + (l & 15);
    const int lg   = l >> 4;
    const unsigned short* afb = afrag_g + (size_t)l * 8;

    f32x4 acc[4][4];  // [band][mt]
    #pragma unroll
    for (int bd = 0; bd < 4; ++bd)
        #pragma unroll
        for (int mt = 0; mt < 4; ++mt)
            acc[bd][mt] = (f32x4){0.f, 0.f, 0.f, 0.f};

    const int rkey = ((site >> 1) & 7) << 4;
    #pragma unroll
    for (int bd = 0; bd < 4; ++bd) {
        const int rb = site * 512 + bd * 128;
        bf16x8 bfr0 = *(const bf16x8*)(&lds_sb[rb + ((lg * 16)      ^ rkey)]);
        bf16x8 bfr1 = *(const bf16x8*)(&lds_sb[rb + ((lg * 16 + 64) ^ rkey)]);
        #pragma unroll
        for (int mt = 0; mt < 4; ++mt) {
            bf16x8 a0 = *(const bf16x8*)(afb + (size_t)((bd * 2 + 0) * 4 + mt) * 512);
            bf16x8 a1 = *(const bf16x8*)(afb + (size_t)((bd * 2 + 1) * 4 + mt) * 512);
            acc[bd][mt] = __builtin_amdgcn_mfma_f32_16x16x32_bf16(a0, bfr0, acc[bd][mt], 0, 0, 0);
            acc[bd][mt] = __builtin_amdgcn_mfma_f32_16x16x32_bf16(a1, bfr1, acc[bd][mt], 0, 0, 0);
        }
    }

    // ---- epilogue: inverse Haar recombine + bias, coalesced float2 stores ----
    const int wb = w0 + 2 * site;
    float* ob = out + (size_t)b * 64 * 65536 + (size_t)h0 * 256 + wb;
    #pragma unroll
    for (int mt = 0; mt < 4; ++mt) {
        const int ob0 = mt * 16 + lg * 4;
        f32x4 bc0 = *(const f32x4*)(&bcomb[  0 + ob0]);
        f32x4 bc1 = *(const f32x4*)(&bcomb[ 64 + ob0]);
        f32x4 bc2 = *(const f32x4*)(&bcomb[128 + ob0]);
        f32x4 bc3 = *(const f32x4*)(&bcomb[192 + ob0]);
        #pragma unroll
        for (int r = 0; r < 4; ++r) {
            float y0 = acc[0][mt][r];  // LL
            float y1 = acc[1][mt][r];  // LH (high-H)
            float y2 = acc[2][mt][r];  // HL (high-W)
            float y3 = acc[3][mt][r];  // HH
            float s01 = y0 + y1, d01 = y0 - y1;
            float s23 = y2 + y3, d23 = y2 - y3;
            float e00 = 0.5f * (s01 + s23) + bc0[r];
            float e01 = 0.5f * (s01 - s23) + bc1[r];
            float e10 = 0.5f * (d01 + d23) + bc2[r];
            float e11 = 0.5f * (d01 - d23) + bc3[r];
            float* po = ob + (size_t)(ob0 + r) * 65536;
            float2 v0; v0.x = e00; v0.y = e01;
            float2 v1; v1.x = e10; v1.y = e11;
            *(float2*)po         = v0;
            *(float2*)(po + 256) = v1;
        }
    }
}

extern "C" void kernel_launch(void* const* d_in, const int* in_sizes, int n_in,
                              void* d_out, int out_size, void* d_ws, size_t ws_size,
                              hipStream_t stream) {
    const float* x   = (const float*)d_in[0];
    const float* wLL = (const float*)d_in[1];
    const float* bLL = (const float*)d_in[2];
    const float* wLH = (const float*)d_in[3];
    const float* bLH = (const float*)d_in[4];
    const float* wHL = (const float*)d_in[5];
    const float* bHL = (const float*)d_in[6];
    const float* wHH = (const float*)d_in[7];
    const float* bHH = (const float*)d_in[8];
    float* out = (float*)d_out;

    unsigned short* afrag = (unsigned short*)d_ws;              // 32768 B
    float* bcomb = (float*)((char*)d_ws + 32768);               // 1024 B

    wvc_prep<<<1, 256, 0, stream>>>(wLL, bLL, wLH, bLH, wHL, bHL, wHH, bHH,
                                    afrag, bcomb);
    wvc_main<<<dim3(2, 128, 8), 256, 0, stream>>>(x, afrag, bcomb, out);
}